// Round 6
// baseline (183.841 us; speedup 1.0000x reference)
//
#include <hip/hip_runtime.h>

#define T_LEN 3000
#define DM 1280
#define NUM_HEADS 20
#define N_CH 4
#define CHUNK 750
#define CHUNK_PAD 768
#define T_PAD 3072

typedef __bf16 bf16x8 __attribute__((ext_vector_type(8)));
typedef float f32x4 __attribute__((ext_vector_type(4)));

typedef const __attribute__((address_space(1))) void* gas_p;
typedef __attribute__((address_space(3))) void* las_p;
#define GLOAD16(g, l) __builtin_amdgcn_global_load_lds((gas_p)(g), (las_p)(l), 16, 0, 0)

__device__ __forceinline__ unsigned short f2bf(float f) {
  union { float f; unsigned u; } x; x.f = f;
  unsigned r = x.u + 0x7FFFu + ((x.u >> 16) & 1u);
  return (unsigned short)(r >> 16);
}

// ---------------- fp32 -> bf16 with zero-fill of pad rows ----------------
__global__ __launch_bounds__(256) void cvt_bf16_kernel(
    const float* __restrict__ in, unsigned short* __restrict__ out) {
  int i = blockIdx.x * 256 + threadIdx.x;
  ushort4 o;
  if (i < T_LEN * DM / 4) {
    const float4 v = ((const float4*)in)[i];
    o.x = f2bf(v.x); o.y = f2bf(v.y); o.z = f2bf(v.z); o.w = f2bf(v.w);
  } else {
    o.x = 0; o.y = 0; o.z = 0; o.w = 0;
  }
  ((ushort4*)out)[i] = o;
}

// ------- transpose 4x 1280x1280 fp32 -> bf16 concat: out[z][n][k] = w[z][k][n]
__global__ __launch_bounds__(256) void tr_bf16_kernel(
    const float* __restrict__ w0, const float* __restrict__ w1,
    const float* __restrict__ w2, const float* __restrict__ w3,
    unsigned short* __restrict__ out) {
  const int z = blockIdx.z;
  const float* in = z == 0 ? w0 : (z == 1 ? w1 : (z == 2 ? w2 : w3));
  unsigned short* o = out + (size_t)z * DM * DM;
  __shared__ float tile[32][33];
  const int x = threadIdx.x, y0 = threadIdx.y;
  const int n0 = blockIdx.x * 32, k0 = blockIdx.y * 32;
  for (int y = y0; y < 32; y += 8) tile[y][x] = in[(k0 + y) * DM + n0 + x];
  __syncthreads();
  for (int y = y0; y < 32; y += 8) o[(n0 + y) * DM + k0 + x] = f2bf(tile[x][y]);
}

// ---------------- zero V chunk-pad columns (NaN guard for P=0 * V) ----------
__global__ __launch_bounds__(256) void vpad_zero_kernel(unsigned short* __restrict__ Vtb) {
  int i = blockIdx.x * 256 + threadIdx.x;
  if (i >= NUM_HEADS * 64 * N_CH * (CHUNK_PAD - CHUNK)) return;
  int c = i % (CHUNK_PAD - CHUNK); int r = i / (CHUNK_PAD - CHUNK);
  int ch = r % N_CH; int row = r / N_CH;
  Vtb[(size_t)row * T_PAD + ch * CHUNK_PAD + CHUNK + c] = 0;
}

// ---------------- GEMM: C[3072 x N] = A[3072][1280] @ Bt^T + bias -----------
// 3-slot ring, BK=32, counted vmcnt(4) (never 0 in steady state), raw
// s_barrier. Natural grid order (bx fastest -> per-XCD A-panel L2 residency,
// FETCH ~47MB). 48 KiB LDS -> 3 blocks/CU (>= grid's 2.8). 256 thr, 4x4 acc.
// MODE 0: fused QKV, grid (24, 30); sec = by/10: 0->Q(1/8), 1->K, 2->V^T
// MODE 1: out-proj, grid (24, 10), fp32 dst
template <int MODE>
__global__ __launch_bounds__(256) void gemm_kernel(
    const unsigned short* __restrict__ A, const unsigned short* __restrict__ Bt,
    const float* __restrict__ b0, const float* __restrict__ b1, const float* __restrict__ b2,
    unsigned short* __restrict__ dq, unsigned short* __restrict__ dk,
    unsigned short* __restrict__ dv, float* __restrict__ df) {
  __shared__ unsigned short As[3][128 * 32];
  __shared__ unsigned short Bs[3][128 * 32];
  const int tid = threadIdx.x;
  const int lane = tid & 63, wave = tid >> 6;
  const int h = lane >> 4, lr = lane & 15;
  const int wm = wave >> 1, wn = wave & 1;
  const int t0 = blockIdx.x * 128, n0 = blockIdx.y * 128;

  // staging: per wave two 16-row groups of A and of B; lane covers
  // row = grp*16 + (lane>>2), 16B chunk c4 = lane&3, source chunk c4 ^ ((row>>1)&3)
  const int srow = lane >> 2;
  const int c4 = lane & 3;
  const int r0 = wave * 32 + srow;
  const int r1 = r0 + 16;
  const unsigned short* a0p = A + (size_t)(t0 + r0) * DM + ((c4 ^ ((r0 >> 1) & 3)) * 8);
  const unsigned short* a1p = A + (size_t)(t0 + r1) * DM + ((c4 ^ ((r1 >> 1) & 3)) * 8);
  const unsigned short* b0p = Bt + (size_t)(n0 + r0) * DM + ((c4 ^ ((r0 >> 1) & 3)) * 8);
  const unsigned short* b1p = Bt + (size_t)(n0 + r1) * DM + ((c4 ^ ((r1 >> 1) & 3)) * 8);

  f32x4 acc[4][4];
  const f32x4 zero4 = {0.f, 0.f, 0.f, 0.f};
#pragma unroll
  for (int i = 0; i < 4; i++)
#pragma unroll
    for (int j = 0; j < 4; j++) acc[i][j] = zero4;

#define G_STAGE(SP, kt) do {                                         \
    const size_t ko_ = (size_t)(kt) * 32;                            \
    GLOAD16(a0p + ko_, &As[SP][(wave * 32) * 32]);                   \
    GLOAD16(a1p + ko_, &As[SP][(wave * 32 + 16) * 32]);              \
    GLOAD16(b0p + ko_, &Bs[SP][(wave * 32) * 32]);                   \
    GLOAD16(b1p + ko_, &Bs[SP][(wave * 32 + 16) * 32]);              \
  } while (0)

  const int NT = DM / 32;  // 40

#define K_STEP(kt, SL, SP) do {                                                \
    if ((kt) + 2 < NT) G_STAGE(SP, (kt) + 2);                                  \
    bf16x8 a[4], b[4];                                                         \
    _Pragma("unroll")                                                          \
    for (int mi = 0; mi < 4; mi++) {                                           \
      const int row = wm * 64 + mi * 16 + lr;                                  \
      a[mi] = *(const bf16x8*)&As[SL][row * 32 + (h ^ ((row >> 1) & 3)) * 8];  \
    }                                                                          \
    _Pragma("unroll")                                                          \
    for (int ni = 0; ni < 4; ni++) {                                           \
      const int col = wn * 64 + ni * 16 + lr;                                  \
      b[ni] = *(const bf16x8*)&Bs[SL][col * 32 + (h ^ ((col >> 1) & 3)) * 8];  \
    }                                                                          \
    _Pragma("unroll")                                                          \
    for (int mi = 0; mi < 4; mi++)                                             \
      _Pragma("unroll")                                                        \
      for (int ni = 0; ni < 4; ni++)                                           \
        acc[mi][ni] = __builtin_amdgcn_mfma_f32_16x16x32_bf16(a[mi], b[ni], acc[mi][ni], 0, 0, 0); \
    if ((kt) + 1 < NT) {                                                       \
      if ((kt) + 2 < NT) { asm volatile("s_waitcnt vmcnt(4)" ::: "memory"); }  \
      else               { asm volatile("s_waitcnt vmcnt(0)" ::: "memory"); }  \
      __builtin_amdgcn_s_barrier();                                            \
      asm volatile("" ::: "memory");                                           \
    }                                                                          \
  } while (0)

  // prologue: tiles 0,1 staged; wait tile0 resident (tile1 stays in flight)
  G_STAGE(0, 0);
  G_STAGE(1, 1);
  asm volatile("s_waitcnt vmcnt(4)" ::: "memory");
  __builtin_amdgcn_s_barrier();
  asm volatile("" ::: "memory");

  for (int kt = 0; kt < NT - 1; kt += 3) {  // steps 0..38
    K_STEP(kt, 0, 2);
    K_STEP(kt + 1, 1, 0);
    K_STEP(kt + 2, 2, 1);
  }
  K_STEP(NT - 1, 0, 2);  // step 39 (39 % 3 == 0)
#undef K_STEP
#undef G_STAGE

  const int sec = (MODE == 0) ? ((int)blockIdx.y / 10) : 0;
  const float* bias = (MODE == 0) ? (sec == 0 ? b0 : (sec == 1 ? b1 : b2)) : b0;
  const float qs = (MODE == 0 && sec == 0) ? 0.125f : 1.0f;
#pragma unroll
  for (int mi = 0; mi < 4; mi++) {
#pragma unroll
    for (int j = 0; j < 4; j++) {
      int t = t0 + wm * 64 + mi * 16 + h * 4 + j;
      if (t >= T_LEN) continue;
#pragma unroll
      for (int ni = 0; ni < 4; ni++) {
        int n = n0 + wn * 64 + ni * 16 + lr;
        if (MODE == 0) {
          int nn = n - sec * DM;
          float v = (acc[mi][ni][j] + bias[nn]) * qs;
          if (sec < 2) {
            unsigned short* dst = sec == 0 ? dq : dk;
            dst[(size_t)(nn >> 6) * (T_PAD * 64) + (size_t)t * 64 + (nn & 63)] = f2bf(v);
          } else {
            int ch = t / CHUNK, s = t - ch * CHUNK;
            dv[(size_t)(nn >> 6) * (64 * T_PAD) + (size_t)(nn & 63) * T_PAD + ch * CHUNK_PAD + s] = f2bf(v);
          }
        } else {
          df[(size_t)t * DM + n] = acc[mi][ni][j] + bias[n];
        }
      }
    }
  }
}

// ---------------- fused block-diagonal attention ----------------------------
__global__ __launch_bounds__(256) void attn_kernel(
    const unsigned short* __restrict__ Qb, const unsigned short* __restrict__ Kb,
    const unsigned short* __restrict__ Vtb, unsigned short* __restrict__ Ctx) {
  __shared__ unsigned short Ks[2][64][64];
  __shared__ unsigned short Vs[2][64][64];
  __shared__ unsigned short Ps[4][16][64];
  const int tid = threadIdx.x;
  const int lane = tid & 63, wave = tid >> 6;
  const int h = lane >> 4, lr = lane & 15;
  const int rs = lane >> 3;
  const int c8 = (lane & 7) ^ rs;
  int bid = blockIdx.x;
  const int qt = bid % 12; bid /= 12;
  const int ch = bid % N_CH; bid /= N_CH;
  const int hh = bid;

  const unsigned short* Qh = Qb + (size_t)hh * (T_PAD * 64);
  const unsigned short* Kh = Kb + (size_t)hh * (T_PAD * 64) + (size_t)(ch * CHUNK) * 64 + c8 * 8;
  const unsigned short* Vh = Vtb + (size_t)hh * (64 * T_PAD) + ch * CHUNK_PAD + c8 * 8;

  const int qrow0 = qt * 64 + wave * 16;
  const int tq = ch * CHUNK + qrow0 + lr;
  bf16x8 aq[2];
#pragma unroll
  for (int kk = 0; kk < 2; kk++)
    aq[kk] = *(const bf16x8*)(Qh + (size_t)tq * 64 + kk * 32 + h * 8);

  const f32x4 zero4 = {0.f, 0.f, 0.f, 0.f};
  f32x4 oacc[4];
#pragma unroll
  for (int i = 0; i < 4; i++) oacc[i] = zero4;
  float l_part[4] = {0.f, 0.f, 0.f, 0.f};

#define A_STAGE(buf, kt) do {                                                   \
    const int s0_ = (kt) * 64;                                                  \
    _Pragma("unroll")                                                           \
    for (int i_ = 0; i_ < 2; ++i_) {                                            \
      const int blk_ = wave * 2 + i_;                                           \
      const int r_ = blk_ * 8 + rs;                                             \
      GLOAD16(Kh + (size_t)(s0_ + r_) * 64, &Ks[buf][blk_ * 8][0]);             \
      GLOAD16(Vh + (size_t)r_ * T_PAD + s0_, &Vs[buf][blk_ * 8][0]);            \
    } } while (0)

  A_STAGE(0, 0);
  __syncthreads();
  int cur = 0;
  for (int kt = 0; kt < 12; ++kt) {
    if (kt + 1 < 12) A_STAGE(cur ^ 1, kt + 1);

    f32x4 sacc[4];
#pragma unroll
    for (int i = 0; i < 4; i++) sacc[i] = zero4;
#pragma unroll
    for (int kk = 0; kk < 2; kk++) {
      const int csw = ((kk * 4 + h) ^ (lr & 7)) * 8;
      bf16x8 bk[4];
#pragma unroll
      for (int ni = 0; ni < 4; ni++) bk[ni] = *(const bf16x8*)&Ks[cur][ni * 16 + lr][csw];
#pragma unroll
      for (int ni = 0; ni < 4; ni++)
        sacc[ni] = __builtin_amdgcn_mfma_f32_16x16x32_bf16(aq[kk], bk[ni], sacc[ni], 0, 0, 0);
    }

    const bool last = (kt == 11);
    float pexp[4][4];
#pragma unroll
    for (int ni = 0; ni < 4; ni++) {
#pragma unroll
      for (int j = 0; j < 4; j++) {
        float e = __expf(sacc[ni][j]);
        if (last && (ni * 16 + lr >= CHUNK - 704)) e = 0.f;
        pexp[ni][j] = e;
        l_part[j] += e;
      }
    }

#pragma unroll
    for (int ni = 0; ni < 4; ni++) {
#pragma unroll
      for (int j = 0; j < 4; j++) {
        int row = h * 4 + j;
        int col = ni * 16 + lr;
        Ps[wave][row][((col >> 3) ^ (row & 7)) * 8 + (col & 7)] = f2bf(pexp[ni][j]);
      }
    }

#pragma unroll
    for (int kk = 0; kk < 2; kk++) {
      const int csw = ((kk * 4 + h) ^ (lr & 7)) * 8;
      bf16x8 ap = *(const bf16x8*)&Ps[wave][lr][csw];
      bf16x8 bv[4];
#pragma unroll
      for (int nd = 0; nd < 4; nd++) bv[nd] = *(const bf16x8*)&Vs[cur][nd * 16 + lr][csw];
#pragma unroll
      for (int nd = 0; nd < 4; nd++)
        oacc[nd] = __builtin_amdgcn_mfma_f32_16x16x32_bf16(ap, bv[nd], oacc[nd], 0, 0, 0);
    }
    __syncthreads();
    cur ^= 1;
  }
#undef A_STAGE

#pragma unroll
  for (int j = 0; j < 4; j++) {
    float l = l_part[j];
#pragma unroll
    for (int off = 1; off < 16; off <<= 1) l += __shfl_xor(l, off, 64);
    int qr = qrow0 + h * 4 + j;
    if (qr >= CHUNK) continue;
    int t = ch * CHUNK + qr;
    float inv = 1.f / l;
#pragma unroll
    for (int nd = 0; nd < 4; nd++) {
      int d = nd * 16 + lr;
      Ctx[(size_t)t * DM + hh * 64 + d] = f2bf(oacc[nd][j] * inv);
    }
  }
}

extern "C" void kernel_launch(void* const* d_in, const int* in_sizes, int n_in,
                              void* d_out, int out_size, void* d_ws, size_t ws_size,
                              hipStream_t stream) {
  const float* hs = (const float*)d_in[0];
  const float* wq = (const float*)d_in[2];
  const float* bq = (const float*)d_in[3];
  const float* wk = (const float*)d_in[4];
  const float* bk = (const float*)d_in[5];
  const float* wv = (const float*)d_in[6];
  const float* bv = (const float*)d_in[7];
  const float* wo = (const float*)d_in[8];
  const float* bo = (const float*)d_in[9];

  char* ws = (char*)d_ws;
  unsigned short* Xb = (unsigned short*)ws;   ws += (size_t)T_PAD * DM * 2;
  unsigned short* Wcat = (unsigned short*)ws; ws += (size_t)4 * DM * DM * 2;
  unsigned short* Qb = (unsigned short*)ws;   ws += (size_t)NUM_HEADS * T_PAD * 64 * 2;
  unsigned short* Kb = (unsigned short*)ws;   ws += (size_t)NUM_HEADS * T_PAD * 64 * 2;
  unsigned short* Vtb = (unsigned short*)ws;  ws += (size_t)NUM_HEADS * 64 * T_PAD * 2;
  unsigned short* Ctx = (unsigned short*)ws;  ws += (size_t)T_PAD * DM * 2;

  cvt_bf16_kernel<<<T_PAD * DM / 4 / 256, 256, 0, stream>>>(hs, Xb);
  tr_bf16_kernel<<<dim3(40, 40, 4), dim3(32, 8), 0, stream>>>(wq, wk, wv, wo, Wcat);
  vpad_zero_kernel<<<(NUM_HEADS * 64 * N_CH * (CHUNK_PAD - CHUNK) + 255) / 256, 256, 0, stream>>>(Vtb);

  gemm_kernel<0><<<dim3(24, 30), 256, 0, stream>>>(Xb, Wcat, bq, bk, bv, Qb, Kb, Vtb, nullptr);

  attn_kernel<<<NUM_HEADS * N_CH * 12, 256, 0, stream>>>(Qb, Kb, Vtb, Ctx);

  gemm_kernel<1><<<dim3(24, 10), 256, 0, stream>>>(Ctx, Wcat + (size_t)3 * DM * DM, bo, nullptr, nullptr,
                                                   nullptr, nullptr, nullptr, (float*)d_out);
}

// Round 7
// 129.335 us; speedup vs baseline: 1.4214x; 1.4214x over previous
//
#include <hip/hip_runtime.h>

#define T_LEN 3000
#define DM 1280
#define NUM_HEADS 20
#define N_CH 4
#define CHUNK 750
#define CHUNK_PAD 768
#define T_PAD 3072

typedef __bf16 bf16x8 __attribute__((ext_vector_type(8)));
typedef float f32x4 __attribute__((ext_vector_type(4)));

typedef const __attribute__((address_space(1))) void* gas_p;
typedef __attribute__((address_space(3))) void* las_p;
#define GLOAD16(g, l) __builtin_amdgcn_global_load_lds((gas_p)(g), (las_p)(l), 16, 0, 0)

__device__ __forceinline__ unsigned short f2bf(float f) {
  union { float f; unsigned u; } x; x.f = f;
  unsigned r = x.u + 0x7FFFu + ((x.u >> 16) & 1u);
  return (unsigned short)(r >> 16);
}

// ---------------- fp32 -> bf16 with zero-fill of pad rows ----------------
__global__ __launch_bounds__(256) void cvt_bf16_kernel(
    const float* __restrict__ in, unsigned short* __restrict__ out) {
  int i = blockIdx.x * 256 + threadIdx.x;
  ushort4 o;
  if (i < T_LEN * DM / 4) {
    const float4 v = ((const float4*)in)[i];
    o.x = f2bf(v.x); o.y = f2bf(v.y); o.z = f2bf(v.z); o.w = f2bf(v.w);
  } else {
    o.x = 0; o.y = 0; o.z = 0; o.w = 0;
  }
  ((ushort4*)out)[i] = o;
}

// ------- transpose 4x 1280x1280 fp32 -> bf16 concat: out[z][n][k] = w[z][k][n]
__global__ __launch_bounds__(256) void tr_bf16_kernel(
    const float* __restrict__ w0, const float* __restrict__ w1,
    const float* __restrict__ w2, const float* __restrict__ w3,
    unsigned short* __restrict__ out) {
  const int z = blockIdx.z;
  const float* in = z == 0 ? w0 : (z == 1 ? w1 : (z == 2 ? w2 : w3));
  unsigned short* o = out + (size_t)z * DM * DM;
  __shared__ float tile[32][33];
  const int x = threadIdx.x, y0 = threadIdx.y;
  const int n0 = blockIdx.x * 32, k0 = blockIdx.y * 32;
  for (int y = y0; y < 32; y += 8) tile[y][x] = in[(k0 + y) * DM + n0 + x];
  __syncthreads();
  for (int y = y0; y < 32; y += 8) o[(n0 + y) * DM + k0 + x] = f2bf(tile[x][y]);
}

// ---------------- zero V chunk-pad columns (NaN guard for P=0 * V) ----------
__global__ __launch_bounds__(256) void vpad_zero_kernel(unsigned short* __restrict__ Vtb) {
  int i = blockIdx.x * 256 + threadIdx.x;
  if (i >= NUM_HEADS * 64 * N_CH * (CHUNK_PAD - CHUNK)) return;
  int c = i % (CHUNK_PAD - CHUNK); int r = i / (CHUNK_PAD - CHUNK);
  int ch = r % N_CH; int row = r / N_CH;
  Vtb[(size_t)row * T_PAD + ch * CHUNK_PAD + CHUNK + c] = 0;
}

// ---------------- GEMM: C[3072 x N] = A[3072][1280] @ Bt^T + bias -----------
// R3-proven m97 sync structure (stage -> barrier -> compute -> barrier),
// tile shrunk to 128x64 for grid-driven latency hiding: QKV 1440 blocks
// (5.6/CU), LDS 24 KiB (6 blocks/CU allowed). 4 waves, wave-tile 64x32.
// MODE 0: fused QKV, grid (24, 60); sec = by/20: 0->Q(1/8), 1->K, 2->V^T
// MODE 1: out-proj, grid (24, 20), fp32 dst
template <int MODE>
__global__ __launch_bounds__(256) void gemm_kernel(
    const unsigned short* __restrict__ A, const unsigned short* __restrict__ Bt,
    const float* __restrict__ b0, const float* __restrict__ b1, const float* __restrict__ b2,
    unsigned short* __restrict__ dq, unsigned short* __restrict__ dk,
    unsigned short* __restrict__ dv, float* __restrict__ df) {
  __shared__ unsigned short As[128][64];
  __shared__ unsigned short Bs[64][64];
  const int tid = threadIdx.x;
  const int lane = tid & 63, wave = tid >> 6;
  const int h = lane >> 4, lr = lane & 15;
  const int wm = wave >> 1, wn = wave & 1;      // 2x2 wave grid, wave-tile 64x32
  const int t0 = blockIdx.x * 128, n0 = blockIdx.y * 64;
  const int rs = lane >> 3;              // sub-row within an 8-row block
  const int c8 = (lane & 7) ^ rs;        // inverse-swizzled source chunk

  const unsigned short* Ab = A + (size_t)t0 * DM + c8 * 8;
  const unsigned short* Bb = Bt + (size_t)n0 * DM + c8 * 8;

  f32x4 acc[4][2];
  const f32x4 zero4 = {0.f, 0.f, 0.f, 0.f};
#pragma unroll
  for (int i = 0; i < 4; i++)
#pragma unroll
    for (int j = 0; j < 2; j++) acc[i][j] = zero4;

  const int NT = DM / 64;  // 20
  for (int kt = 0; kt < NT; ++kt) {
    const int k0 = kt * 64;
#pragma unroll
    for (int i = 0; i < 4; ++i) {        // A: 16 8-row blocks, 4 per wave
      const int blk = wave * 4 + i;
      GLOAD16(Ab + (size_t)(blk * 8 + rs) * DM + k0, &As[blk * 8][0]);
    }
#pragma unroll
    for (int i = 0; i < 2; ++i) {        // B: 8 8-row blocks, 2 per wave
      const int blk = wave * 2 + i;
      GLOAD16(Bb + (size_t)(blk * 8 + rs) * DM + k0, &Bs[blk * 8][0]);
    }
    __syncthreads();  // drains vmcnt -> tile visible
#pragma unroll
    for (int kk = 0; kk < 2; ++kk) {
      bf16x8 a[4], b[2];
      const int csw = ((kk * 4 + h) ^ (lr & 7)) * 8;
#pragma unroll
      for (int mi = 0; mi < 4; mi++) a[mi] = *(const bf16x8*)&As[wm * 64 + mi * 16 + lr][csw];
#pragma unroll
      for (int ni = 0; ni < 2; ni++) b[ni] = *(const bf16x8*)&Bs[wn * 32 + ni * 16 + lr][csw];
#pragma unroll
      for (int mi = 0; mi < 4; mi++)
#pragma unroll
        for (int ni = 0; ni < 2; ni++)
          acc[mi][ni] = __builtin_amdgcn_mfma_f32_16x16x32_bf16(a[mi], b[ni], acc[mi][ni], 0, 0, 0);
    }
    __syncthreads();  // all waves done reading before next overwrite
  }

  const int sec = (MODE == 0) ? ((int)blockIdx.y / 20) : 0;
  const float* bias = (MODE == 0) ? (sec == 0 ? b0 : (sec == 1 ? b1 : b2)) : b0;
  const float qs = (MODE == 0 && sec == 0) ? 0.125f : 1.0f;
#pragma unroll
  for (int mi = 0; mi < 4; mi++) {
#pragma unroll
    for (int j = 0; j < 4; j++) {
      int t = t0 + wm * 64 + mi * 16 + h * 4 + j;
      if (t >= T_LEN) continue;
#pragma unroll
      for (int ni = 0; ni < 2; ni++) {
        int n = n0 + wn * 32 + ni * 16 + lr;
        if (MODE == 0) {
          int nn = n - sec * DM;
          float v = (acc[mi][ni][j] + bias[nn]) * qs;
          if (sec < 2) {
            unsigned short* dst = sec == 0 ? dq : dk;
            dst[(size_t)(nn >> 6) * (T_PAD * 64) + (size_t)t * 64 + (nn & 63)] = f2bf(v);
          } else {
            int ch = t / CHUNK, s = t - ch * CHUNK;
            dv[(size_t)(nn >> 6) * (64 * T_PAD) + (size_t)(nn & 63) * T_PAD + ch * CHUNK_PAD + s] = f2bf(v);
          }
        } else {
          df[(size_t)t * DM + n] = acc[mi][ni][j] + bias[n];
        }
      }
    }
  }
}

// ---------------- fused block-diagonal attention ----------------------------
__global__ __launch_bounds__(256) void attn_kernel(
    const unsigned short* __restrict__ Qb, const unsigned short* __restrict__ Kb,
    const unsigned short* __restrict__ Vtb, unsigned short* __restrict__ Ctx) {
  __shared__ unsigned short Ks[2][64][64];
  __shared__ unsigned short Vs[2][64][64];
  __shared__ unsigned short Ps[4][16][64];
  const int tid = threadIdx.x;
  const int lane = tid & 63, wave = tid >> 6;
  const int h = lane >> 4, lr = lane & 15;
  const int rs = lane >> 3;
  const int c8 = (lane & 7) ^ rs;
  int bid = blockIdx.x;
  const int qt = bid % 12; bid /= 12;
  const int ch = bid % N_CH; bid /= N_CH;
  const int hh = bid;

  const unsigned short* Qh = Qb + (size_t)hh * (T_PAD * 64);
  const unsigned short* Kh = Kb + (size_t)hh * (T_PAD * 64) + (size_t)(ch * CHUNK) * 64 + c8 * 8;
  const unsigned short* Vh = Vtb + (size_t)hh * (64 * T_PAD) + ch * CHUNK_PAD + c8 * 8;

  const int qrow0 = qt * 64 + wave * 16;
  const int tq = ch * CHUNK + qrow0 + lr;
  bf16x8 aq[2];
#pragma unroll
  for (int kk = 0; kk < 2; kk++)
    aq[kk] = *(const bf16x8*)(Qh + (size_t)tq * 64 + kk * 32 + h * 8);

  const f32x4 zero4 = {0.f, 0.f, 0.f, 0.f};
  f32x4 oacc[4];
#pragma unroll
  for (int i = 0; i < 4; i++) oacc[i] = zero4;
  float l_part[4] = {0.f, 0.f, 0.f, 0.f};

#define A_STAGE(buf, kt) do {                                                   \
    const int s0_ = (kt) * 64;                                                  \
    _Pragma("unroll")                                                           \
    for (int i_ = 0; i_ < 2; ++i_) {                                            \
      const int blk_ = wave * 2 + i_;                                           \
      const int r_ = blk_ * 8 + rs;                                             \
      GLOAD16(Kh + (size_t)(s0_ + r_) * 64, &Ks[buf][blk_ * 8][0]);             \
      GLOAD16(Vh + (size_t)r_ * T_PAD + s0_, &Vs[buf][blk_ * 8][0]);            \
    } } while (0)

  A_STAGE(0, 0);
  __syncthreads();
  int cur = 0;
  for (int kt = 0; kt < 12; ++kt) {
    if (kt + 1 < 12) A_STAGE(cur ^ 1, kt + 1);

    f32x4 sacc[4];
#pragma unroll
    for (int i = 0; i < 4; i++) sacc[i] = zero4;
#pragma unroll
    for (int kk = 0; kk < 2; kk++) {
      const int csw = ((kk * 4 + h) ^ (lr & 7)) * 8;
      bf16x8 bk[4];
#pragma unroll
      for (int ni = 0; ni < 4; ni++) bk[ni] = *(const bf16x8*)&Ks[cur][ni * 16 + lr][csw];
#pragma unroll
      for (int ni = 0; ni < 4; ni++)
        sacc[ni] = __builtin_amdgcn_mfma_f32_16x16x32_bf16(aq[kk], bk[ni], sacc[ni], 0, 0, 0);
    }

    const bool last = (kt == 11);
    float pexp[4][4];
#pragma unroll
    for (int ni = 0; ni < 4; ni++) {
#pragma unroll
      for (int j = 0; j < 4; j++) {
        float e = __expf(sacc[ni][j]);
        if (last && (ni * 16 + lr >= CHUNK - 704)) e = 0.f;
        pexp[ni][j] = e;
        l_part[j] += e;
      }
    }

#pragma unroll
    for (int ni = 0; ni < 4; ni++) {
#pragma unroll
      for (int j = 0; j < 4; j++) {
        int row = h * 4 + j;
        int col = ni * 16 + lr;
        Ps[wave][row][((col >> 3) ^ (row & 7)) * 8 + (col & 7)] = f2bf(pexp[ni][j]);
      }
    }

#pragma unroll
    for (int kk = 0; kk < 2; kk++) {
      const int csw = ((kk * 4 + h) ^ (lr & 7)) * 8;
      bf16x8 ap = *(const bf16x8*)&Ps[wave][lr][csw];
      bf16x8 bv[4];
#pragma unroll
      for (int nd = 0; nd < 4; nd++) bv[nd] = *(const bf16x8*)&Vs[cur][nd * 16 + lr][csw];
#pragma unroll
      for (int nd = 0; nd < 4; nd++)
        oacc[nd] = __builtin_amdgcn_mfma_f32_16x16x32_bf16(ap, bv[nd], oacc[nd], 0, 0, 0);
    }
    __syncthreads();
    cur ^= 1;
  }
#undef A_STAGE

#pragma unroll
  for (int j = 0; j < 4; j++) {
    float l = l_part[j];
#pragma unroll
    for (int off = 1; off < 16; off <<= 1) l += __shfl_xor(l, off, 64);
    int qr = qrow0 + h * 4 + j;
    if (qr >= CHUNK) continue;
    int t = ch * CHUNK + qr;
    float inv = 1.f / l;
#pragma unroll
    for (int nd = 0; nd < 4; nd++) {
      int d = nd * 16 + lr;
      Ctx[(size_t)t * DM + hh * 64 + d] = f2bf(oacc[nd][j] * inv);
    }
  }
}

extern "C" void kernel_launch(void* const* d_in, const int* in_sizes, int n_in,
                              void* d_out, int out_size, void* d_ws, size_t ws_size,
                              hipStream_t stream) {
  const float* hs = (const float*)d_in[0];
  const float* wq = (const float*)d_in[2];
  const float* bq = (const float*)d_in[3];
  const float* wk = (const float*)d_in[4];
  const float* bk = (const float*)d_in[5];
  const float* wv = (const float*)d_in[6];
  const float* bv = (const float*)d_in[7];
  const float* wo = (const float*)d_in[8];
  const float* bo = (const float*)d_in[9];

  char* ws = (char*)d_ws;
  unsigned short* Xb = (unsigned short*)ws;   ws += (size_t)T_PAD * DM * 2;
  unsigned short* Wcat = (unsigned short*)ws; ws += (size_t)4 * DM * DM * 2;
  unsigned short* Qb = (unsigned short*)ws;   ws += (size_t)NUM_HEADS * T_PAD * 64 * 2;
  unsigned short* Kb = (unsigned short*)ws;   ws += (size_t)NUM_HEADS * T_PAD * 64 * 2;
  unsigned short* Vtb = (unsigned short*)ws;  ws += (size_t)NUM_HEADS * 64 * T_PAD * 2;
  unsigned short* Ctx = (unsigned short*)ws;  ws += (size_t)T_PAD * DM * 2;

  cvt_bf16_kernel<<<T_PAD * DM / 4 / 256, 256, 0, stream>>>(hs, Xb);
  tr_bf16_kernel<<<dim3(40, 40, 4), dim3(32, 8), 0, stream>>>(wq, wk, wv, wo, Wcat);
  vpad_zero_kernel<<<(NUM_HEADS * 64 * N_CH * (CHUNK_PAD - CHUNK) + 255) / 256, 256, 0, stream>>>(Vtb);

  gemm_kernel<0><<<dim3(24, 60), 256, 0, stream>>>(Xb, Wcat, bq, bk, bv, Qb, Kb, Vtb, nullptr);

  attn_kernel<<<NUM_HEADS * N_CH * 12, 256, 0, stream>>>(Qb, Kb, Vtb, Ctx);

  gemm_kernel<1><<<dim3(24, 20), 256, 0, stream>>>(Ctx, Wcat + (size_t)3 * DM * DM, bo, nullptr, nullptr,
                                                   nullptr, nullptr, nullptr, (float*)d_out);
}